// Round 7
// baseline (14691.435 us; speedup 1.0000x reference)
//
#include <hip/hip_runtime.h>
#include <stdint.h>

typedef unsigned long long ull;

// ================= DIAGNOSTIC ROUND 2: localize the grid-NN bug =============
// Output: ONLY the proven round-0 brute-force path (passes by construction).
// v1 (framework brute) / v2 (sorted brute) / v3 (grid-NN) each write g_nn and
// are compared bitwise vs brute P. Counts encoded as named spin dispatches:
//   mmX = round(dur(chamfer_spinX) / dur(chamfer_spincal)), cap 8.
// g_mmD counts v3 mismatches whose dist halves are bitwise EQUAL (tie flips).
// ===========================================================================

#define NP     8192
#define NCLOUD 4
#define GDIM   8
#define NCELL  512
#define GO     (-4.25f)
#define GW     (1.0625f)      // 17/16, exact fp32
#define MARGIN_REL 1.001f
#define MARGIN_ABS 1e-3f

__device__ float4 g_spts[NCLOUD][NP];
__device__ int    g_sidx[NCLOUD][NP];
__device__ int    g_cstart[NCLOUD][NCELL+1];
__device__ ull    g_nn[4 * NP];
__device__ int    g_mmA, g_mmB, g_mmC, g_mmD;
__device__ int    g_one = 1;        // calibration "count" (identical codegen)

__device__ __forceinline__ uint32_t enc_f32(float f) {
    uint32_t u = __float_as_uint(f);
    return (u & 0x80000000u) ? ~u : (u | 0x80000000u);
}

__device__ __forceinline__ float sq_np(float x, float y, float z) {
    return __fadd_rn(__fadd_rn(__fmul_rn(x, x), __fmul_rn(y, y)), __fmul_rn(z, z));
}

__device__ __forceinline__ int cellof(float v) {
    int c = (int)floorf((v - GO) * (1.0f / GW));
    return min(GDIM - 1, max(0, c));
}

__device__ __forceinline__ float axdist(int c, float q) {
    float lo  = fmaf((float)c, GW, GO);
    float hi  = lo + GW;
    float dlo = (c == 0)        ? 0.0f : (lo - q);
    float dhi = (c == GDIM - 1) ? 0.0f : (q - hi);
    return fmaxf(fmaxf(dlo, dhi), 0.0f);
}

// decode gt -> (par, dir, b, n) shared by v1/v2/v3
#define NN_DECODE \
    int gt  = blockIdx.x * 256 + threadIdx.x; \
    int par = gt & 1; \
    int q   = gt >> 1; \
    int dir = q >> 14; \
    int rem = q & 16383; \
    int b   = rem >> 13; \
    int n   = rem & 8191;

#define PAIR_MERGE(bestv) { \
    unsigned lo32 = (unsigned)(bestv), hi32 = (unsigned)((bestv) >> 32); \
    unsigned olo = __shfl_xor(lo32, 1), ohi = __shfl_xor(hi32, 1); \
    ull other = ((ull)ohi << 32) | olo; \
    if (other < (bestv)) (bestv) = other; }

// -------- prep: counting sort (unchanged) + counter reset -------------------
__global__ void __launch_bounds__(1024) chamfer_prep(
    const float* __restrict__ xyz1, const float* __restrict__ xyz2)
{
    __shared__ int h[NCELL];
    __shared__ int cur[NCELL];
    int cid = blockIdx.x;
    const float* src = (cid < 2) ? (xyz1 + (size_t)cid * NP * 3)
                                 : (xyz2 + (size_t)(cid - 2) * NP * 3);
    int t = threadIdx.x;

    if (cid == 0 && t == 0) { g_mmA = 0; g_mmB = 0; g_mmC = 0; g_mmD = 0; }

    if (t < NCELL) h[t] = 0;
    __syncthreads();

    float px[8], py[8], pz[8];
    int   pc[8];
    #pragma unroll
    for (int k = 0; k < 8; ++k) {
        int p = t + k * 1024;
        const float* s = src + (size_t)p * 3;
        px[k] = s[0]; py[k] = s[1]; pz[k] = s[2];
        int cx = cellof(px[k]), cy = cellof(py[k]), cz = cellof(pz[k]);
        pc[k] = (cz * GDIM + cy) * GDIM + cx;
        atomicAdd(&h[pc[k]], 1);
    }
    __syncthreads();

    for (int ofs = 1; ofs < NCELL; ofs <<= 1) {
        int v = 0;
        if (t < NCELL) { v = h[t]; if (t >= ofs) v += h[t - ofs]; }
        __syncthreads();
        if (t < NCELL) h[t] = v;
        __syncthreads();
    }
    if (t < NCELL) {
        int excl = (t == 0) ? 0 : h[t - 1];
        cur[t] = excl;
        g_cstart[cid][t] = excl;
        if (t == NCELL - 1) g_cstart[cid][NCELL] = h[NCELL - 1];
    }
    __syncthreads();

    #pragma unroll
    for (int k = 0; k < 8; ++k) {
        int pos = atomicAdd(&cur[pc[k]], 1);
        g_spts[cid][pos] = make_float4(px[k], py[k], pz[k], sq_np(px[k], py[k], pz[k]));
        g_sidx[cid][pos] = t + k * 1024;
    }
}

__device__ __forceinline__ void scan_cell(
    const float4* __restrict__ pts, const int* __restrict__ sidx,
    int j0, int j1, float qx, float qy, float qz, float qs,
    ull& best, float& bestf)
{
    for (int j = j0; j < j1; ++j) {
        float4 p = pts[j];
        float cross = __fadd_rn(__fadd_rn(__fmul_rn(qx, p.x), __fmul_rn(qy, p.y)),
                                __fmul_rn(qz, p.z));
        float s = __fadd_rn(qs, p.w);
        float d = fmaf(-2.0f, cross, s);
        ull c = ((ull)enc_f32(d) << 32) | (uint32_t)sidx[j];
        if (c < best) { best = c; bestf = d; }
    }
}

// -------- v1: brute force in the nn framework, straight from inputs --------
__global__ void __launch_bounds__(256) chamfer_v1(
    const float* __restrict__ xyz1, const float* __restrict__ xyz2)
{
    NN_DECODE
    const float* qsrc = dir ? (xyz2 + (size_t)b * NP * 3) : (xyz1 + (size_t)b * NP * 3);
    const float* csrc = dir ? (xyz1 + (size_t)b * NP * 3) : (xyz2 + (size_t)b * NP * 3);
    float qx = qsrc[(size_t)n * 3], qy = qsrc[(size_t)n * 3 + 1], qz = qsrc[(size_t)n * 3 + 2];
    float qs = sq_np(qx, qy, qz);
    ull best = ~0ull;
    for (int j = par; j < NP; j += 2) {
        float px = csrc[(size_t)j * 3], py = csrc[(size_t)j * 3 + 1], pz = csrc[(size_t)j * 3 + 2];
        float ps = sq_np(px, py, pz);
        float cross = __fadd_rn(__fadd_rn(__fmul_rn(qx, px), __fmul_rn(qy, py)),
                                __fmul_rn(qz, pz));
        float s = __fadd_rn(qs, ps);
        float d = fmaf(-2.0f, cross, s);
        ull c = ((ull)enc_f32(d) << 32) | (uint32_t)j;
        if (c < best) best = c;
    }
    PAIR_MERGE(best)
    if (par == 0) g_nn[(dir * 2 + b) * NP + n] = best;
}

// -------- v2: brute force over the SORTED arrays (adds prep dependency) ----
__global__ void __launch_bounds__(256) chamfer_v2()
{
    NN_DECODE
    int cq = dir ? 2 + b : b;
    int cc = dir ? b : 2 + b;
    const float4* __restrict__ cpts = g_spts[cc];
    const int*    __restrict__ cidx = g_sidx[cc];
    float4 qp = g_spts[cq][n];
    float qx = qp.x, qy = qp.y, qz = qp.z, qs = qp.w;
    int eout = (dir * 2 + b) * NP + g_sidx[cq][n];
    ull best = ~0ull;
    float bestf = 3.4e38f;
    scan_cell(cpts, cidx, par == 0 ? 0 : 0, 0, qx, qy, qz, qs, best, bestf); // no-op, keep shape
    for (int j = par; j < NP; j += 2) {
        float4 p = cpts[j];
        float cross = __fadd_rn(__fadd_rn(__fmul_rn(qx, p.x), __fmul_rn(qy, p.y)),
                                __fmul_rn(qz, p.z));
        float s = __fadd_rn(qs, p.w);
        float d = fmaf(-2.0f, cross, s);
        ull c = ((ull)enc_f32(d) << 32) | (uint32_t)cidx[j];
        if (c < best) best = c;
    }
    PAIR_MERGE(best)
    if (par == 0) g_nn[eout] = best;
}

// -------- v3: the full grid-NN under test (round-5/6 logic) ----------------
__global__ void __launch_bounds__(256) chamfer_v3()
{
    NN_DECODE
    int cq = dir ? 2 + b : b;
    int cc = dir ? b : 2 + b;
    const float4* __restrict__ cpts = g_spts[cc];
    const int*    __restrict__ cidx = g_sidx[cc];
    const int*    __restrict__ csid = g_cstart[cc];

    float4 qp = g_spts[cq][n];
    float qx = qp.x, qy = qp.y, qz = qp.z, qs = qp.w;
    int eout = (dir * 2 + b) * NP + g_sidx[cq][n];

    ull best = ~0ull;
    float bestf = 3.4e38f;

    int hx = cellof(qx), hy = cellof(qy), hz = cellof(qz);

    for (int iz = max(hz - 1, 0); iz <= min(hz + 1, GDIM - 1); ++iz)
      for (int iy = max(hy - 1, 0); iy <= min(hy + 1, GDIM - 1); ++iy)
        for (int ix = max(hx - 1, 0); ix <= min(hx + 1, GDIM - 1); ++ix) {
          if (((ix + iy + iz) & 1) != par) continue;
          int cell = (iz * GDIM + iy) * GDIM + ix;
          scan_cell(cpts, cidx, csid[cell], csid[cell + 1], qx, qy, qz, qs, best, bestf);
        }

    {   // seed merge (share min + its float across the pair)
        unsigned lo32 = (unsigned)best, hi32 = (unsigned)(best >> 32);
        unsigned olo = __shfl_xor(lo32, 1), ohi = __shfl_xor(hi32, 1);
        float    obf = __shfl_xor(bestf, 1);
        ull other = ((ull)ohi << 32) | olo;
        if (other < best) { best = other; bestf = obf; }
    }

    for (int cz = 0; cz < GDIM; ++cz) {
        float dz  = axdist(cz, qz);
        float dz2 = dz * dz;
        if (dz2 > fmaf(bestf, MARGIN_REL, MARGIN_ABS)) continue;
        for (int cy = 0; cy < GDIM; ++cy) {
            float dy  = axdist(cy, qy);
            float dyz = fmaf(dy, dy, dz2);
            if (dyz > fmaf(bestf, MARGIN_REL, MARGIN_ABS)) continue;
            for (int cx = par; cx < GDIM; cx += 2) {
                float dxv = axdist(cx, qx);
                float lb  = fmaf(dxv, dxv, dyz);
                if (lb > fmaf(bestf, MARGIN_REL, MARGIN_ABS)) continue;
                int cell = (cz * GDIM + cy) * GDIM + cx;
                scan_cell(cpts, cidx, csid[cell], csid[cell + 1], qx, qy, qz, qs, best, bestf);
            }
        }
    }

    PAIR_MERGE(best)
    if (par == 0) g_nn[eout] = best;
}

// -------- probe: count g_nn vs P mismatches into the selected counter ------
__global__ void __launch_bounds__(256) chamfer_probe(const ull* __restrict__ P, int sel)
{
    int e = blockIdx.x * 256 + threadIdx.x;
    if (e < 4 * NP) {
        ull a = P[e], v = g_nn[e];
        if (a != v) {
            if (sel == 0)      atomicAdd(&g_mmA, 1);
            else if (sel == 1) atomicAdd(&g_mmB, 1);
            else {
                atomicAdd(&g_mmC, 1);
                if ((a >> 32) == (v >> 32)) atomicAdd(&g_mmD, 1);  // tie flip
            }
        }
    }
}

// -------- spins: duration = min(count,8) * unit; cal = exactly 1 unit ------
#define SPIN_BODY(CNT) \
    int mm = (CNT); if (mm > 8) mm = 8; \
    long iters = (long)mm * 32768; \
    float x = 1.0f; \
    for (long i = 0; i < iters; ++i) x = fmaf(x, 1.0000001f, 1e-9f); \
    asm volatile("" :: "v"(x));

__global__ void __launch_bounds__(64) chamfer_spincal() { SPIN_BODY(g_one) }
__global__ void __launch_bounds__(64) chamfer_spinA()   { SPIN_BODY(g_mmA) }
__global__ void __launch_bounds__(64) chamfer_spinB()   { SPIN_BODY(g_mmB) }
__global__ void __launch_bounds__(64) chamfer_spinC()   { SPIN_BODY(g_mmC) }
__global__ void __launch_bounds__(64) chamfer_spinD()   { SPIN_BODY(g_mmD) }

// ================= legacy brute-force path (round-0, proven) ================
#define TPB   256
#define Q     4
#define CHUNK 128

__global__ void __launch_bounds__(TPB) chamfer_pass1(
    const float* __restrict__ xyz1, const float* __restrict__ xyz2,
    ull* __restrict__ P, int B, int N, int M)
{
    __shared__ float4 pts[CHUNK];

    int z   = blockIdx.z;
    int dir = z / B;
    int b   = z - dir * B;

    const float* src; const float* dst; int Ns, Nd; size_t ebase;
    if (dir == 0) { src = xyz1; dst = xyz2; Ns = N; Nd = M; ebase = (size_t)b * N; }
    else          { src = xyz2; dst = xyz1; Ns = M; Nd = N; ebase = (size_t)B * N + (size_t)b * M; }

    int t     = threadIdx.x;
    int mbase = blockIdx.y * CHUNK;

    for (int i = t; i < CHUNK; i += TPB) {
        int m = mbase + i;
        if (m < Nd) {
            const float* p = dst + ((size_t)b * Nd + m) * 3;
            float x = p[0], y = p[1], zz = p[2];
            pts[i] = make_float4(x, y, zz, sq_np(x, y, zz));
        } else {
            pts[i] = make_float4(0.f, 0.f, 0.f, 3.0e38f);
        }
    }

    int n0 = blockIdx.x * (TPB * Q) + t;
    float qx[Q], qy[Q], qz[Q], qs[Q];
    #pragma unroll
    for (int k = 0; k < Q; ++k) {
        int n = n0 + k * TPB;
        if (n < Ns) {
            const float* p = src + ((size_t)b * Ns + n) * 3;
            qx[k] = p[0]; qy[k] = p[1]; qz[k] = p[2];
            qs[k] = sq_np(qx[k], qy[k], qz[k]);
        } else { qx[k] = 0.f; qy[k] = 0.f; qz[k] = 0.f; qs[k] = 0.f; }
    }
    __syncthreads();

    float best[Q];
    int   bidx[Q];
    #pragma unroll
    for (int k = 0; k < Q; ++k) { best[k] = 3.4e38f; bidx[k] = 0; }

    #pragma unroll 4
    for (int i = 0; i < CHUNK; ++i) {
        float4 qv = pts[i];
        #pragma unroll
        for (int k = 0; k < Q; ++k) {
            float cross = __fadd_rn(__fadd_rn(__fmul_rn(qx[k], qv.x), __fmul_rn(qy[k], qv.y)),
                                    __fmul_rn(qz[k], qv.z));
            float s = __fadd_rn(qs[k], qv.w);
            float d = fmaf(-2.0f, cross, s);
            if (d < best[k]) { best[k] = d; bidx[k] = mbase + i; }
        }
    }

    #pragma unroll
    for (int k = 0; k < Q; ++k) {
        int n = n0 + k * TPB;
        if (n < Ns) {
            ull packed = ((ull)enc_f32(best[k]) << 32) | (unsigned int)bidx[k];
            atomicMin(&P[ebase + n], packed);
        }
    }
}

__global__ void __launch_bounds__(256) chamfer_unpack(
    const ull* __restrict__ P, float* __restrict__ out, int entries)
{
    int e = blockIdx.x * 256 + threadIdx.x;
    if (e < entries) {
        ull pk = P[e];
        uint32_t encu = (uint32_t)(pk >> 32);
        uint32_t idx  = (uint32_t)pk;
        uint32_t bits = (encu & 0x80000000u) ? (encu & 0x7FFFFFFFu) : ~encu;
        out[e]           = __uint_as_float(bits);
        out[entries + e] = (float)idx;
    }
}

__global__ void __launch_bounds__(1024) chamfer_unpack_inplace(float* __restrict__ out)
{
    const int entries = 32768;
    const ull* P = (const ull*)out;
    int t = threadIdx.x;
    ull v[32];
    #pragma unroll
    for (int k = 0; k < 32; ++k) v[k] = P[t + k * 1024];
    __syncthreads();
    #pragma unroll
    for (int k = 0; k < 32; ++k) {
        int e = t + k * 1024;
        ull pk = v[k];
        uint32_t encu = (uint32_t)(pk >> 32);
        uint32_t idx  = (uint32_t)pk;
        uint32_t bits = (encu & 0x80000000u) ? (encu & 0x7FFFFFFFu) : ~encu;
        out[e]           = __uint_as_float(bits);
        out[entries + e] = (float)idx;
    }
}

extern "C" void kernel_launch(void* const* d_in, const int* in_sizes, int n_in,
                              void* d_out, int out_size, void* d_ws, size_t ws_size,
                              hipStream_t stream) {
    const float* xyz1 = (const float*)d_in[0];
    const float* xyz2 = (const float*)d_in[1];
    const int B = 2;
    const int N = in_sizes[0] / (B * 3);   // 8192
    const int M = in_sizes[1] / (B * 3);   // 8192

    float* out = (float*)d_out;
    const int entries = B * N + B * M;     // 32768
    const size_t pbytes = (size_t)entries * sizeof(ull);

    const bool probe = (B == 2 && N == NP && M == NP);

    int maxP = (N > M) ? N : M;
    dim3 grid((maxP + TPB * Q - 1) / (TPB * Q), (maxP + CHUNK - 1) / CHUNK, 2 * B);

    ull* P;
    bool inplace;
    if (ws_size >= pbytes) { P = (ull*)d_ws;  inplace = false; hipMemsetAsync(d_ws, 0xFF, pbytes, stream); }
    else                   { P = (ull*)d_out; inplace = true;  hipMemsetAsync(d_out, 0xFF, pbytes, stream); }

    chamfer_pass1<<<grid, TPB, 0, stream>>>(xyz1, xyz2, P, B, N, M);

    if (probe) {
        chamfer_prep<<<4, 1024, 0, stream>>>(xyz1, xyz2);
        chamfer_v1<<<256, 256, 0, stream>>>(xyz1, xyz2);
        chamfer_probe<<<128, 256, 0, stream>>>(P, 0);
        chamfer_v2<<<256, 256, 0, stream>>>();
        chamfer_probe<<<128, 256, 0, stream>>>(P, 1);
        chamfer_v3<<<256, 256, 0, stream>>>();
        chamfer_probe<<<128, 256, 0, stream>>>(P, 2);
        chamfer_spincal<<<1, 64, 0, stream>>>();
        chamfer_spinA<<<1, 64, 0, stream>>>();
        chamfer_spinB<<<1, 64, 0, stream>>>();
        chamfer_spinC<<<1, 64, 0, stream>>>();
        chamfer_spinD<<<1, 64, 0, stream>>>();
    }

    if (!inplace) {
        chamfer_unpack<<<(entries + 255) / 256, 256, 0, stream>>>(P, out, entries);
    } else {
        if (entries == 32768) {
            chamfer_unpack_inplace<<<1, 1024, 0, stream>>>(out);
        } else {
            chamfer_unpack<<<1, 1, 0, stream>>>((const ull*)d_out, out, 0);
        }
    }
}

// Round 8
// 1952.338 us; speedup vs baseline: 7.5250x; 7.5250x over previous
//
#include <hip/hip_runtime.h>
#include <stdint.h>

typedef unsigned long long ull;

// ================= single-kernel within-block grid-NN ======================
// All producer->consumer state lives in LDS (sort tables) or registers.
// Global memory use: READ inputs (host-written, coherent), WRITE out
// (host-read after sync) — exactly the two proven-safe directions.
// No cross-kernel device globals, no atomics to global, no memset, 1 dispatch.
// ===========================================================================

#define NP     8192
#define GDIM   8
#define NCELL  512
#define GO     (-4.25f)       // grid origin (exact fp32)
#define GW     (1.0625f)      // cell width 17/16 (exact fp32)
#define MARGIN_REL 1.001f     // prune only if lb > bestf*1.001 + 1e-3:
#define MARGIN_ABS 1e-3f      // ~40x the worst-case expansion-noise (~2.5e-5)
#define QPB    128            // queries per block
#define BLKT   1024           // threads per block (8 threads per query)

// Monotone float->uint mapping so unsigned compare == float compare.
__device__ __forceinline__ uint32_t enc_f32(float f) {
    uint32_t u = __float_as_uint(f);
    return (u & 0x80000000u) ? ~u : (u | 0x80000000u);
}

// Bitwise-replicate numpy fp32: sq = (x*x + y*y) + z*z, rounded each op, no fma.
__device__ __forceinline__ float sq_np(float x, float y, float z) {
    return __fadd_rn(__fadd_rn(__fmul_rn(x, x), __fmul_rn(y, y)), __fmul_rn(z, z));
}

__device__ __forceinline__ int cellof(float v) {
    int c = (int)floorf((v - GO) * (1.0f / GW));
    return min(GDIM - 1, max(0, c));
}

// Per-axis distance to cell c's slab; edge cells extend to +-inf outward so
// clamped stray points (|coord| > 4.25) provably lie inside their cell's box.
__device__ __forceinline__ float axdist(int c, float q) {
    float lo  = fmaf((float)c, GW, GO);
    float hi  = lo + GW;
    float dlo = (c == 0)        ? 0.0f : (lo - q);
    float dhi = (c == GDIM - 1) ? 0.0f : (q - hi);
    return fmaxf(fmaxf(dlo, dhi), 0.0f);
}

// Scan candidates [j0,j1) of one cell. EXACT numpy-fp32 d chain (proven round
// 0). Packed (enc(d)<<32)|idx: u64 min == lexicographic (d, idx) min == numpy
// first-occurrence argmin. Coords gathered from the read-only input (L2-hot).
__device__ __forceinline__ void scan_cell_g(
    const float* __restrict__ csrc, const unsigned short* sidx,
    int j0, int j1, float qx, float qy, float qz, float qs,
    ull& best, float& bestf)
{
    for (int j = j0; j < j1; ++j) {
        int idx = sidx[j];
        float px = csrc[(size_t)idx * 3];
        float py = csrc[(size_t)idx * 3 + 1];
        float pz = csrc[(size_t)idx * 3 + 2];
        float ps = sq_np(px, py, pz);
        float cross = __fadd_rn(__fadd_rn(__fmul_rn(qx, px), __fmul_rn(qy, py)),
                                __fmul_rn(qz, pz));
        float s = __fadd_rn(qs, ps);
        float d = fmaf(-2.0f, cross, s);         // == fl(s - 2*cross) bitwise
        ull c = ((ull)enc_f32(d) << 32) | (uint32_t)idx;
        if (c < best) { best = c; bestf = d; }
    }
}

// grid: 256 blocks = 4 (dir,b) x 64 slices; 1024 threads = 128 queries x 8.
__global__ void __launch_bounds__(BLKT, 4) chamfer_block(
    const float* __restrict__ xyz1, const float* __restrict__ xyz2,
    float* __restrict__ out)
{
    __shared__ unsigned short sidx[NP];   // 16 KB: candidate indices by cell
    __shared__ int cs[NCELL + 1];         // cell start offsets
    __shared__ int h[NCELL];              // histogram, reused as scatter cursor

    const int t     = threadIdx.x;
    const int blk   = blockIdx.x;         // 0..255
    const int db    = blk >> 6;           // dir*2 + b
    const int dir   = db >> 1;
    const int b     = db & 1;
    const int slice = blk & 63;

    const float* __restrict__ qsrc = dir ? (xyz2 + (size_t)b * NP * 3)
                                         : (xyz1 + (size_t)b * NP * 3);
    const float* __restrict__ csrc = dir ? (xyz1 + (size_t)b * NP * 3)
                                         : (xyz2 + (size_t)b * NP * 3);

    // ---- phase 1: counting-sort candidate INDICES by cell (LDS only) ----
    if (t < NCELL) h[t] = 0;
    __syncthreads();
    int pc[8];
    #pragma unroll
    for (int k = 0; k < 8; ++k) {
        int p = t + k * BLKT;
        float x = csrc[(size_t)p * 3];
        float y = csrc[(size_t)p * 3 + 1];
        float z = csrc[(size_t)p * 3 + 2];
        pc[k] = (cellof(z) * GDIM + cellof(y)) * GDIM + cellof(x);
        atomicAdd(&h[pc[k]], 1);
    }
    __syncthreads();
    for (int ofs = 1; ofs < NCELL; ofs <<= 1) {   // inclusive Hillis-Steele
        int v = 0;
        if (t < NCELL) { v = h[t]; if (t >= ofs) v += h[t - ofs]; }
        __syncthreads();
        if (t < NCELL) h[t] = v;
        __syncthreads();
    }
    int excl = 0;
    if (t < NCELL) excl = (t == 0) ? 0 : h[t - 1];
    __syncthreads();
    if (t < NCELL) { cs[t] = excl; h[t] = excl; }
    if (t == 0) cs[NCELL] = NP;
    __syncthreads();
    #pragma unroll
    for (int k = 0; k < 8; ++k) {
        int pos = atomicAdd(&h[pc[k]], 1);        // unique slot in cell range
        sidx[pos] = (unsigned short)(t + k * BLKT);
    }
    __syncthreads();

    // ---- phase 2: 8 threads per query: seed 27-cube + bounded sweep ----
    const int ql = t >> 3, tq = t & 7;
    const int n  = slice * QPB + ql;              // query index in its cloud
    float qx = qsrc[(size_t)n * 3];
    float qy = qsrc[(size_t)n * 3 + 1];
    float qz = qsrc[(size_t)n * 3 + 2];
    float qs = sq_np(qx, qy, qz);

    ull best = ~0ull;
    float bestf = 3.4e38f;
    int hx = cellof(qx), hy = cellof(qy), hz = cellof(qz);

    // seed: 27-neighborhood, cells round-robined over the 8 lanes
    int cnt = 0;
    for (int iz = max(hz - 1, 0); iz <= min(hz + 1, GDIM - 1); ++iz)
      for (int iy = max(hy - 1, 0); iy <= min(hy + 1, GDIM - 1); ++iy)
        for (int ix = max(hx - 1, 0); ix <= min(hx + 1, GDIM - 1); ++ix) {
          if ((cnt++ & 7) != tq) continue;
          int cell = (iz * GDIM + iy) * GDIM + ix;
          scan_cell_g(csrc, sidx, cs[cell], cs[cell + 1], qx, qy, qz, qs, best, bestf);
        }

    // merge seed across the 8-lane group (groups are 8-aligned in the wave)
    #pragma unroll
    for (int mask = 1; mask <= 4; mask <<= 1) {
        unsigned lo = (unsigned)best, hi = (unsigned)(best >> 32);
        unsigned olo = __shfl_xor(lo, mask), ohi = __shfl_xor(hi, mask);
        float    obf = __shfl_xor(bestf, mask);
        ull other = ((ull)ohi << 32) | olo;
        if (other < best) { best = other; bestf = obf; }
    }

    // sweep: lane tq owns x-column cx==tq; (cz,cy) bounds are query-uniform.
    // 27-cube cells already scanned in seed -> skipped. Prune uses the lane's
    // current best (>= final best) -> sound. Empty-seed case: bestf=3.4e38 ->
    // margin overflows to +inf -> nothing pruned -> still exact.
    for (int cz = 0; cz < GDIM; ++cz) {
        float dz  = axdist(cz, qz);
        float dz2 = dz * dz;
        if (dz2 > fmaf(bestf, MARGIN_REL, MARGIN_ABS)) continue;
        for (int cy = 0; cy < GDIM; ++cy) {
            float dy  = axdist(cy, qy);
            float dyz = fmaf(dy, dy, dz2);
            if (dyz > fmaf(bestf, MARGIN_REL, MARGIN_ABS)) continue;
            int cx = tq;
            if (cz >= hz - 1 && cz <= hz + 1 &&
                cy >= hy - 1 && cy <= hy + 1 &&
                cx >= hx - 1 && cx <= hx + 1) continue;   // seeded already
            float dxv = axdist(cx, qx);
            float lb  = fmaf(dxv, dxv, dyz);
            if (lb > fmaf(bestf, MARGIN_REL, MARGIN_ABS)) continue;
            int cell = (cz * GDIM + cy) * GDIM + cx;
            scan_cell_g(csrc, sidx, cs[cell], cs[cell + 1], qx, qy, qz, qs, best, bestf);
        }
    }

    // final merge across the 8-lane group
    #pragma unroll
    for (int mask = 1; mask <= 4; mask <<= 1) {
        unsigned lo = (unsigned)best, hi = (unsigned)(best >> 32);
        unsigned olo = __shfl_xor(lo, mask), ohi = __shfl_xor(hi, mask);
        ull other = ((ull)ohi << 32) | olo;
        if (other < best) best = other;
    }

    if (tq == 0) {
        int eout = db * NP + n;                   // same layout as legacy path
        uint32_t encu = (uint32_t)(best >> 32);
        uint32_t idx  = (uint32_t)best;
        uint32_t bits = (encu & 0x80000000u) ? (encu & 0x7FFFFFFFu) : ~encu;
        out[eout]          = __uint_as_float(bits);
        out[4 * NP + eout] = (float)idx;
    }
}

// ================= legacy brute-force path (round-0, proven) ================
#define TPB   256
#define Q     4
#define CHUNK 128

__global__ void __launch_bounds__(TPB) chamfer_pass1(
    const float* __restrict__ xyz1, const float* __restrict__ xyz2,
    ull* __restrict__ P, int B, int N, int M)
{
    __shared__ float4 pts[CHUNK];

    int z   = blockIdx.z;
    int dir = z / B;
    int b   = z - dir * B;

    const float* src; const float* dst; int Ns, Nd; size_t ebase;
    if (dir == 0) { src = xyz1; dst = xyz2; Ns = N; Nd = M; ebase = (size_t)b * N; }
    else          { src = xyz2; dst = xyz1; Ns = M; Nd = N; ebase = (size_t)B * N + (size_t)b * M; }

    int t     = threadIdx.x;
    int mbase = blockIdx.y * CHUNK;

    for (int i = t; i < CHUNK; i += TPB) {
        int m = mbase + i;
        if (m < Nd) {
            const float* p = dst + ((size_t)b * Nd + m) * 3;
            float x = p[0], y = p[1], zz = p[2];
            pts[i] = make_float4(x, y, zz, sq_np(x, y, zz));
        } else {
            pts[i] = make_float4(0.f, 0.f, 0.f, 3.0e38f);
        }
    }

    int n0 = blockIdx.x * (TPB * Q) + t;
    float qx[Q], qy[Q], qz[Q], qs[Q];
    #pragma unroll
    for (int k = 0; k < Q; ++k) {
        int n = n0 + k * TPB;
        if (n < Ns) {
            const float* p = src + ((size_t)b * Ns + n) * 3;
            qx[k] = p[0]; qy[k] = p[1]; qz[k] = p[2];
            qs[k] = sq_np(qx[k], qy[k], qz[k]);
        } else { qx[k] = 0.f; qy[k] = 0.f; qz[k] = 0.f; qs[k] = 0.f; }
    }
    __syncthreads();

    float best[Q];
    int   bidx[Q];
    #pragma unroll
    for (int k = 0; k < Q; ++k) { best[k] = 3.4e38f; bidx[k] = 0; }

    #pragma unroll 4
    for (int i = 0; i < CHUNK; ++i) {
        float4 qv = pts[i];
        #pragma unroll
        for (int k = 0; k < Q; ++k) {
            float cross = __fadd_rn(__fadd_rn(__fmul_rn(qx[k], qv.x), __fmul_rn(qy[k], qv.y)),
                                    __fmul_rn(qz[k], qv.z));
            float s = __fadd_rn(qs[k], qv.w);
            float d = fmaf(-2.0f, cross, s);
            if (d < best[k]) { best[k] = d; bidx[k] = mbase + i; }
        }
    }

    #pragma unroll
    for (int k = 0; k < Q; ++k) {
        int n = n0 + k * TPB;
        if (n < Ns) {
            ull packed = ((ull)enc_f32(best[k]) << 32) | (unsigned int)bidx[k];
            atomicMin(&P[ebase + n], packed);
        }
    }
}

__global__ void __launch_bounds__(256) chamfer_unpack(
    const ull* __restrict__ P, float* __restrict__ out, int entries)
{
    int e = blockIdx.x * 256 + threadIdx.x;
    if (e < entries) {
        ull pk = P[e];
        uint32_t encu = (uint32_t)(pk >> 32);
        uint32_t idx  = (uint32_t)pk;
        uint32_t bits = (encu & 0x80000000u) ? (encu & 0x7FFFFFFFu) : ~encu;
        out[e]           = __uint_as_float(bits);
        out[entries + e] = (float)idx;
    }
}

__global__ void __launch_bounds__(1024) chamfer_unpack_inplace(float* __restrict__ out)
{
    const int entries = 32768;
    const ull* P = (const ull*)out;
    int t = threadIdx.x;
    ull v[32];
    #pragma unroll
    for (int k = 0; k < 32; ++k) v[k] = P[t + k * 1024];
    __syncthreads();
    #pragma unroll
    for (int k = 0; k < 32; ++k) {
        int e = t + k * 1024;
        ull pk = v[k];
        uint32_t encu = (uint32_t)(pk >> 32);
        uint32_t idx  = (uint32_t)pk;
        uint32_t bits = (encu & 0x80000000u) ? (encu & 0x7FFFFFFFu) : ~encu;
        out[e]           = __uint_as_float(bits);
        out[entries + e] = (float)idx;
    }
}

extern "C" void kernel_launch(void* const* d_in, const int* in_sizes, int n_in,
                              void* d_out, int out_size, void* d_ws, size_t ws_size,
                              hipStream_t stream) {
    const float* xyz1 = (const float*)d_in[0];
    const float* xyz2 = (const float*)d_in[1];
    const int B = 2;
    const int N = in_sizes[0] / (B * 3);   // 8192
    const int M = in_sizes[1] / (B * 3);   // 8192

    float* out = (float*)d_out;
    const int entries = B * N + B * M;     // 32768
    const size_t pbytes = (size_t)entries * sizeof(ull);

    // Fast path: one self-contained dispatch, LDS-only intermediate state.
    if (B == 2 && N == NP && M == NP) {
        chamfer_block<<<256, BLKT, 0, stream>>>(xyz1, xyz2, out);
        return;
    }

    // Legacy 3-dispatch brute force (proven at 111.6 us) for other shapes.
    int maxP = (N > M) ? N : M;
    dim3 grid((maxP + TPB * Q - 1) / (TPB * Q), (maxP + CHUNK - 1) / CHUNK, 2 * B);

    if (ws_size >= pbytes) {
        ull* P = (ull*)d_ws;
        hipMemsetAsync(d_ws, 0xFF, pbytes, stream);
        chamfer_pass1<<<grid, TPB, 0, stream>>>(xyz1, xyz2, P, B, N, M);
        chamfer_unpack<<<(entries + 255) / 256, 256, 0, stream>>>(P, out, entries);
    } else {
        ull* P = (ull*)d_out;
        hipMemsetAsync(d_out, 0xFF, pbytes, stream);
        chamfer_pass1<<<grid, TPB, 0, stream>>>(xyz1, xyz2, P, B, N, M);
        if (entries == 32768) {
            chamfer_unpack_inplace<<<1, 1024, 0, stream>>>(out);
        } else {
            chamfer_unpack<<<1, 1, 0, stream>>>((const ull*)d_out, out, 0);
        }
    }
}